// Round 1
// baseline (693.758 us; speedup 1.0000x reference)
//
#include <hip/hip_runtime.h>
#include <math.h>

static constexpr int   kB = 4096;
static constexpr int   kG = 512;
static constexpr int   kD = 64;
static constexpr int   kP = kG * kD;
static constexpr float kEps   = 1e-5f;
static constexpr float kSlope = 0.2f;

// ---------------------------------------------------------------------------
// Pass 1: reps[b,g] = leakyrelu(sum_d x[b, idx[g,d]] * W[g,d])
//         + per-group sum / sumsq accumulation for batchnorm.
// Grid (kG/4, kB/256), block 256 (4 waves).
// Wave layout: 4 segments of 16 lanes; segment = one group; lane owns 4
// consecutive d-elements -> float4 (16 B/lane) coalesced loads when idx is
// contiguous (it is arange -> identity).
// ---------------------------------------------------------------------------
template<bool STORE_REPS>
__global__ __launch_bounds__(256) void pass1(const float* __restrict__ x,
                                             const int*   __restrict__ idxw,
                                             const float* __restrict__ W,
                                             float* __restrict__ reps,
                                             float* __restrict__ gsum,
                                             float* __restrict__ gsumsq) {
    const int tid  = threadIdx.x;
    const int w    = tid >> 6;      // wave 0..3
    const int lane = tid & 63;
    const int seg  = lane >> 4;     // group within quad, 0..3
    const int s    = lane & 15;     // lane within segment
    const int q    = blockIdx.x;    // group quad 0..127
    const int g    = 4 * q + seg;
    const int base = g * 64 + 4 * s;

    // idx may arrive as int32 or int64 words (it is arange(G*D)); detect.
    // int32: words [0,1,2,...]  -> stride 1
    // int64: words [0,0,1,0,..] -> stride 2 (little-endian low words)
    const int wstride = (idxw[1] == 0 && idxw[2] == 1) ? 2 : 1;
    const int f0 = idxw[(size_t)(base + 0) * wstride];
    const int f1 = idxw[(size_t)(base + 1) * wstride];
    const int f2 = idxw[(size_t)(base + 2) * wstride];
    const int f3 = idxw[(size_t)(base + 3) * wstride];
    const bool contig = (f1 == f0 + 1) && (f2 == f0 + 2) && (f3 == f0 + 3) &&
                        ((f0 & 3) == 0);
    const float4 wv = *(const float4*)(W + base);

    const int row0 = blockIdx.y * 256 + w * 64;
    float asum = 0.f, asq = 0.f;

    if (contig) {
        #pragma unroll 4
        for (int i = 0; i < 64; ++i) {
            const int b = row0 + i;
            const float4 xv = *(const float4*)(x + (size_t)b * kP + f0);
            float dot = xv.x * wv.x + xv.y * wv.y + xv.z * wv.z + xv.w * wv.w;
            dot += __shfl_xor(dot, 1, 16);
            dot += __shfl_xor(dot, 2, 16);
            dot += __shfl_xor(dot, 4, 16);
            dot += __shfl_xor(dot, 8, 16);
            const float v = dot >= 0.f ? dot : kSlope * dot;
            if (s == 0) {
                if (STORE_REPS) reps[(size_t)b * kG + g] = v;
                asum += v; asq += v * v;
            }
        }
    } else {
        #pragma unroll 2
        for (int i = 0; i < 64; ++i) {
            const int b = row0 + i;
            const float* xr = x + (size_t)b * kP;
            float dot = xr[f0] * wv.x + xr[f1] * wv.y + xr[f2] * wv.z +
                        xr[f3] * wv.w;
            dot += __shfl_xor(dot, 1, 16);
            dot += __shfl_xor(dot, 2, 16);
            dot += __shfl_xor(dot, 4, 16);
            dot += __shfl_xor(dot, 8, 16);
            const float v = dot >= 0.f ? dot : kSlope * dot;
            if (s == 0) {
                if (STORE_REPS) reps[(size_t)b * kG + g] = v;
                asum += v; asq += v * v;
            }
        }
    }

    __shared__ float ls[4][4];
    __shared__ float lq[4][4];
    if (s == 0) { ls[w][seg] = asum; lq[w][seg] = asq; }
    __syncthreads();
    if (tid < 4) {
        atomicAdd(&gsum[4 * q + tid],
                  ls[0][tid] + ls[1][tid] + ls[2][tid] + ls[3][tid]);
        atomicAdd(&gsumsq[4 * q + tid],
                  lq[0][tid] + lq[1][tid] + lq[2][tid] + lq[3][tid]);
    }
}

// ---------------------------------------------------------------------------
// Pass 2: fold batchnorm + final fc into per-group affine coefficients.
//   a[g] = fc_w[g]*gamma[g]*rsqrt(var+eps)
//   c    = fc_b + sum_g fc_w[g]*(beta[g] - gamma[g]*mean[g]*rsqrt(var+eps))
// One block, kG threads.
// ---------------------------------------------------------------------------
__global__ __launch_bounds__(kG) void pass2(const float* __restrict__ gsum,
                                            const float* __restrict__ gsumsq,
                                            const float* __restrict__ gamma,
                                            const float* __restrict__ beta,
                                            const float* __restrict__ fcw,
                                            const float* __restrict__ fcb,
                                            float* __restrict__ acoef,
                                            float* __restrict__ cval) {
    const int g = threadIdx.x;
    const float invB = 1.0f / (float)kB;
    const float mean = gsum[g] * invB;
    float var = gsumsq[g] * invB - mean * mean;
    var = var < 0.f ? 0.f : var;
    const float rs = rsqrtf(var + kEps);
    const float fw = fcw[g];
    const float ga = gamma[g];
    acoef[g] = fw * ga * rs;
    float cg = fw * (beta[g] - ga * mean * rs);

    __shared__ float red[kG];
    red[g] = cg;
    __syncthreads();
    for (int off = kG / 2; off > 0; off >>= 1) {
        if (g < off) red[g] += red[g + off];
        __syncthreads();
    }
    if (g == 0) cval[0] = red[0] + fcb[0];
}

// ---------------------------------------------------------------------------
// Pass 3 (fast path): out[b] = sigmoid(sum_g a[g]*reps[b,g] + c)
// Block 256 = 4 waves, one wave per row; lane reads 8 floats (2x float4,
// contiguous across the wave).
// ---------------------------------------------------------------------------
__global__ __launch_bounds__(256) void pass3(const float* __restrict__ reps,
                                             const float* __restrict__ acoef,
                                             const float* __restrict__ cval,
                                             float* __restrict__ out) {
    const int tid  = threadIdx.x;
    const int w    = tid >> 6;
    const int lane = tid & 63;
    const int b    = blockIdx.x * 4 + w;
    const float* r = reps + (size_t)b * kG;

    float acc = 0.f;
    #pragma unroll
    for (int c = 0; c < 2; ++c) {
        const int o = c * 256 + lane * 4;
        const float4 rv = *(const float4*)(r + o);
        const float4 av = *(const float4*)(acoef + o);
        acc += rv.x * av.x + rv.y * av.y + rv.z * av.z + rv.w * av.w;
    }
    acc += __shfl_xor(acc, 1, 64);
    acc += __shfl_xor(acc, 2, 64);
    acc += __shfl_xor(acc, 4, 64);
    acc += __shfl_xor(acc, 8, 64);
    acc += __shfl_xor(acc, 16, 64);
    acc += __shfl_xor(acc, 32, 64);
    if (lane == 0) {
        const float logit = acc + cval[0];
        out[b] = 1.f / (1.f + expf(-logit));
    }
}

// ---------------------------------------------------------------------------
// Fallback path (tiny workspace): recompute reps on the fly, accumulate
// per-row logit with atomics, then sigmoid.
// ---------------------------------------------------------------------------
__global__ __launch_bounds__(256) void pass3_re(const float* __restrict__ x,
                                                const int*   __restrict__ idxw,
                                                const float* __restrict__ W,
                                                const float* __restrict__ acoef,
                                                float* __restrict__ logit) {
    const int tid  = threadIdx.x;
    const int w    = tid >> 6;
    const int lane = tid & 63;
    const int seg  = lane >> 4;
    const int s    = lane & 15;
    const int q    = blockIdx.x;
    const int g    = 4 * q + seg;
    const int base = g * 64 + 4 * s;

    const int wstride = (idxw[1] == 0 && idxw[2] == 1) ? 2 : 1;
    const int f0 = idxw[(size_t)(base + 0) * wstride];
    const int f1 = idxw[(size_t)(base + 1) * wstride];
    const int f2 = idxw[(size_t)(base + 2) * wstride];
    const int f3 = idxw[(size_t)(base + 3) * wstride];
    const float4 wv = *(const float4*)(W + base);
    const float ag = acoef[g];

    const int row0 = blockIdx.y * 256 + w * 64;
    for (int i = 0; i < 64; ++i) {
        const int b = row0 + i;
        const float* xr = x + (size_t)b * kP;
        float dot = xr[f0] * wv.x + xr[f1] * wv.y + xr[f2] * wv.z +
                    xr[f3] * wv.w;
        dot += __shfl_xor(dot, 1, 16);
        dot += __shfl_xor(dot, 2, 16);
        dot += __shfl_xor(dot, 4, 16);
        dot += __shfl_xor(dot, 8, 16);
        const float v = dot >= 0.f ? dot : kSlope * dot;
        float t = (s == 0) ? ag * v : 0.f;
        t += __shfl_xor(t, 16, 64);
        t += __shfl_xor(t, 32, 64);
        if (lane == 0) atomicAdd(&logit[b], t);
    }
}

__global__ __launch_bounds__(256) void pass4(const float* __restrict__ logit,
                                             const float* __restrict__ cval,
                                             float* __restrict__ out) {
    const int b = blockIdx.x * 256 + threadIdx.x;
    const float l = logit[b] + cval[0];
    out[b] = 1.f / (1.f + expf(-l));
}

// ---------------------------------------------------------------------------
extern "C" void kernel_launch(void* const* d_in, const int* in_sizes, int n_in,
                              void* d_out, int out_size, void* d_ws,
                              size_t ws_size, hipStream_t stream) {
    const float* x     = (const float*)d_in[0];
    const int*   idxw  = (const int*)  d_in[1];
    const float* W     = (const float*)d_in[2];
    const float* gamma = (const float*)d_in[3];
    const float* beta  = (const float*)d_in[4];
    const float* fcw   = (const float*)d_in[5];
    const float* fcb   = (const float*)d_in[6];
    float* out = (float*)d_out;

    const size_t need_fast =
        ((size_t)kB * kG + 3 * (size_t)kG + 16) * sizeof(float);

    if (ws_size >= need_fast) {
        float* reps   = (float*)d_ws;
        float* gsum   = reps + (size_t)kB * kG;
        float* gsumsq = gsum + kG;
        float* acoef  = gsumsq + kG;
        float* cval   = acoef + kG;
        hipMemsetAsync(gsum, 0, 2 * kG * sizeof(float), stream);
        pass1<true><<<dim3(kG / 4, kB / 256), 256, 0, stream>>>(
            x, idxw, W, reps, gsum, gsumsq);
        pass2<<<1, kG, 0, stream>>>(gsum, gsumsq, gamma, beta, fcw, fcb,
                                    acoef, cval);
        pass3<<<kB / 4, 256, 0, stream>>>(reps, acoef, cval, out);
    } else {
        float* gsum   = (float*)d_ws;
        float* gsumsq = gsum + kG;
        float* acoef  = gsumsq + kG;
        float* cval   = acoef + kG;
        float* logit  = cval + 4;
        hipMemsetAsync(gsum, 0, 2 * kG * sizeof(float), stream);
        hipMemsetAsync(logit, 0, kB * sizeof(float), stream);
        pass1<false><<<dim3(kG / 4, kB / 256), 256, 0, stream>>>(
            x, idxw, W, nullptr, gsum, gsumsq);
        pass2<<<1, kG, 0, stream>>>(gsum, gsumsq, gamma, beta, fcw, fcb,
                                    acoef, cval);
        pass3_re<<<dim3(kG / 4, kB / 256), 256, 0, stream>>>(
            x, idxw, W, acoef, logit);
        pass4<<<kB / 256, 256, 0, stream>>>(logit, cval, out);
    }
}

// Round 2
// 692.544 us; speedup vs baseline: 1.0018x; 1.0018x over previous
//
#include <hip/hip_runtime.h>
#include <math.h>

static constexpr int   kB = 4096;
static constexpr int   kG = 512;
static constexpr int   kD = 64;
static constexpr int   kP = kG * kD;
static constexpr int   kYB = kB / 256;   // 16 row-blocks
static constexpr float kEps   = 1e-5f;
static constexpr float kSlope = 0.2f;

// ---------------------------------------------------------------------------
// Pass 1: reps[b,g] = leakyrelu(sum_d x[b, idx[g,d]] * W[g,d])
//         + per-(rowblock, group) partial sum / sumsq (exclusive writes,
//         no atomics, no zero-init needed -> tolerates 0xAA-poisoned ws).
// Grid (kG/4, kYB), block 256 (4 waves).
// Wave layout: 4 segments of 16 lanes; segment = one group; lane owns 4
// consecutive d-elements -> float4 (16 B/lane) coalesced loads when idx is
// contiguous (it is arange -> identity; fallback handles general idx).
// ---------------------------------------------------------------------------
template<bool STORE_REPS>
__global__ __launch_bounds__(256) void pass1(const float* __restrict__ x,
                                             const int*   __restrict__ idxw,
                                             const float* __restrict__ W,
                                             float* __restrict__ reps,
                                             float* __restrict__ psum,
                                             float* __restrict__ psumsq) {
    const int tid  = threadIdx.x;
    const int w    = tid >> 6;      // wave 0..3
    const int lane = tid & 63;
    const int seg  = lane >> 4;     // group within quad, 0..3
    const int s    = lane & 15;     // lane within segment
    const int q    = blockIdx.x;    // group quad 0..127
    const int g    = 4 * q + seg;
    const int base = g * 64 + 4 * s;

    // idx may arrive as int32 or int64 words (it is arange(G*D)); detect.
    // int32: words [0,1,2,...] -> stride 1; int64 LE low words -> stride 2.
    const int wstride = (idxw[1] == 0 && idxw[2] == 1) ? 2 : 1;
    const int f0 = idxw[(size_t)(base + 0) * wstride];
    const int f1 = idxw[(size_t)(base + 1) * wstride];
    const int f2 = idxw[(size_t)(base + 2) * wstride];
    const int f3 = idxw[(size_t)(base + 3) * wstride];
    const bool contig = (f1 == f0 + 1) && (f2 == f0 + 2) && (f3 == f0 + 3) &&
                        ((f0 & 3) == 0);
    const float4 wv = *(const float4*)(W + base);

    const int row0 = blockIdx.y * 256 + w * 64;
    float asum = 0.f, asq = 0.f;

    if (contig) {
        const float4* p = (const float4*)(x + (size_t)row0 * kP + f0);
        float* rp = STORE_REPS ? (reps + (size_t)row0 * kG + g) : nullptr;
        #pragma unroll 4
        for (int i = 0; i < 64; ++i) {
            const float4 xv = *p;
            p += kP / 4;
            float dot = xv.x * wv.x + xv.y * wv.y + xv.z * wv.z + xv.w * wv.w;
            dot += __shfl_xor(dot, 1, 16);
            dot += __shfl_xor(dot, 2, 16);
            dot += __shfl_xor(dot, 4, 16);
            dot += __shfl_xor(dot, 8, 16);
            const float v = dot >= 0.f ? dot : kSlope * dot;
            if (s == 0) {
                if (STORE_REPS) { *rp = v; rp += kG; }
                asum += v; asq += v * v;
            }
        }
    } else {
        #pragma unroll 2
        for (int i = 0; i < 64; ++i) {
            const int b = row0 + i;
            const float* xr = x + (size_t)b * kP;
            float dot = xr[f0] * wv.x + xr[f1] * wv.y + xr[f2] * wv.z +
                        xr[f3] * wv.w;
            dot += __shfl_xor(dot, 1, 16);
            dot += __shfl_xor(dot, 2, 16);
            dot += __shfl_xor(dot, 4, 16);
            dot += __shfl_xor(dot, 8, 16);
            const float v = dot >= 0.f ? dot : kSlope * dot;
            if (s == 0) {
                if (STORE_REPS) reps[(size_t)b * kG + g] = v;
                asum += v; asq += v * v;
            }
        }
    }

    __shared__ float ls[4][4];
    __shared__ float lq[4][4];
    if (s == 0) { ls[w][seg] = asum; lq[w][seg] = asq; }
    __syncthreads();
    if (tid < 4) {
        const int gg = 4 * q + tid;
        psum  [(size_t)blockIdx.y * kG + gg] =
            ls[0][tid] + ls[1][tid] + ls[2][tid] + ls[3][tid];
        psumsq[(size_t)blockIdx.y * kG + gg] =
            lq[0][tid] + lq[1][tid] + lq[2][tid] + lq[3][tid];
    }
}

// ---------------------------------------------------------------------------
// Pass 2: reduce partials, fold batchnorm + final fc into per-group affine:
//   a[g] = fc_w[g]*gamma[g]*rsqrt(var+eps)
//   c    = fc_b + sum_g fc_w[g]*(beta[g] - gamma[g]*mean[g]*rsqrt(var+eps))
// One block, kG threads.
// ---------------------------------------------------------------------------
__global__ __launch_bounds__(kG) void pass2(const float* __restrict__ psum,
                                            const float* __restrict__ psumsq,
                                            const float* __restrict__ gamma,
                                            const float* __restrict__ beta,
                                            const float* __restrict__ fcw,
                                            const float* __restrict__ fcb,
                                            float* __restrict__ acoef,
                                            float* __restrict__ cval) {
    const int g = threadIdx.x;
    float s = 0.f, ss = 0.f;
    #pragma unroll
    for (int y = 0; y < kYB; ++y) {
        s  += psum  [(size_t)y * kG + g];
        ss += psumsq[(size_t)y * kG + g];
    }
    const float invB = 1.0f / (float)kB;
    const float mean = s * invB;
    float var = ss * invB - mean * mean;
    var = var < 0.f ? 0.f : var;
    const float rs = rsqrtf(var + kEps);
    const float fw = fcw[g];
    const float ga = gamma[g];
    acoef[g] = fw * ga * rs;
    float cg = fw * (beta[g] - ga * mean * rs);

    __shared__ float red[kG];
    red[g] = cg;
    __syncthreads();
    for (int off = kG / 2; off > 0; off >>= 1) {
        if (g < off) red[g] += red[g + off];
        __syncthreads();
    }
    if (g == 0) cval[0] = red[0] + fcb[0];
}

// ---------------------------------------------------------------------------
// Pass 3 (fast path): out[b] = sigmoid(sum_g a[g]*reps[b,g] + c)
// Block 256 = 4 waves, one wave per row; lane reads 8 floats (2x float4,
// contiguous across the wave).
// ---------------------------------------------------------------------------
__global__ __launch_bounds__(256) void pass3(const float* __restrict__ reps,
                                             const float* __restrict__ acoef,
                                             const float* __restrict__ cval,
                                             float* __restrict__ out) {
    const int tid  = threadIdx.x;
    const int w    = tid >> 6;
    const int lane = tid & 63;
    const int b    = blockIdx.x * 4 + w;
    const float* r = reps + (size_t)b * kG;

    float acc = 0.f;
    #pragma unroll
    for (int c = 0; c < 2; ++c) {
        const int o = c * 256 + lane * 4;
        const float4 rv = *(const float4*)(r + o);
        const float4 av = *(const float4*)(acoef + o);
        acc += rv.x * av.x + rv.y * av.y + rv.z * av.z + rv.w * av.w;
    }
    acc += __shfl_xor(acc, 1, 64);
    acc += __shfl_xor(acc, 2, 64);
    acc += __shfl_xor(acc, 4, 64);
    acc += __shfl_xor(acc, 8, 64);
    acc += __shfl_xor(acc, 16, 64);
    acc += __shfl_xor(acc, 32, 64);
    if (lane == 0) {
        const float logit = acc + cval[0];
        out[b] = 1.f / (1.f + expf(-logit));
    }
}

// ---------------------------------------------------------------------------
// Fallback path (tiny workspace): recompute reps on the fly, accumulate
// per-row logit with atomics, then sigmoid. Needs zero-init via memset.
// ---------------------------------------------------------------------------
__global__ __launch_bounds__(256) void pass3_re(const float* __restrict__ x,
                                                const int*   __restrict__ idxw,
                                                const float* __restrict__ W,
                                                const float* __restrict__ acoef,
                                                float* __restrict__ logit) {
    const int tid  = threadIdx.x;
    const int w    = tid >> 6;
    const int lane = tid & 63;
    const int seg  = lane >> 4;
    const int s    = lane & 15;
    const int q    = blockIdx.x;
    const int g    = 4 * q + seg;
    const int base = g * 64 + 4 * s;

    const int wstride = (idxw[1] == 0 && idxw[2] == 1) ? 2 : 1;
    const int f0 = idxw[(size_t)(base + 0) * wstride];
    const int f1 = idxw[(size_t)(base + 1) * wstride];
    const int f2 = idxw[(size_t)(base + 2) * wstride];
    const int f3 = idxw[(size_t)(base + 3) * wstride];
    const float4 wv = *(const float4*)(W + base);
    const float ag = acoef[g];

    const int row0 = blockIdx.y * 256 + w * 64;
    for (int i = 0; i < 64; ++i) {
        const int b = row0 + i;
        const float* xr = x + (size_t)b * kP;
        float dot = xr[f0] * wv.x + xr[f1] * wv.y + xr[f2] * wv.z +
                    xr[f3] * wv.w;
        dot += __shfl_xor(dot, 1, 16);
        dot += __shfl_xor(dot, 2, 16);
        dot += __shfl_xor(dot, 4, 16);
        dot += __shfl_xor(dot, 8, 16);
        const float v = dot >= 0.f ? dot : kSlope * dot;
        float t = (s == 0) ? ag * v : 0.f;
        t += __shfl_xor(t, 16, 64);
        t += __shfl_xor(t, 32, 64);
        if (lane == 0) atomicAdd(&logit[b], t);
    }
}

__global__ __launch_bounds__(256) void pass4(const float* __restrict__ logit,
                                             const float* __restrict__ cval,
                                             float* __restrict__ out) {
    const int b = blockIdx.x * 256 + threadIdx.x;
    const float l = logit[b] + cval[0];
    out[b] = 1.f / (1.f + expf(-l));
}

// ---------------------------------------------------------------------------
extern "C" void kernel_launch(void* const* d_in, const int* in_sizes, int n_in,
                              void* d_out, int out_size, void* d_ws,
                              size_t ws_size, hipStream_t stream) {
    const float* x     = (const float*)d_in[0];
    const int*   idxw  = (const int*)  d_in[1];
    const float* W     = (const float*)d_in[2];
    const float* gamma = (const float*)d_in[3];
    const float* beta  = (const float*)d_in[4];
    const float* fcw   = (const float*)d_in[5];
    const float* fcb   = (const float*)d_in[6];
    float* out = (float*)d_out;

    const size_t need_fast =
        ((size_t)kB * kG + (2 * kYB + 1) * (size_t)kG + 16) * sizeof(float);

    if (ws_size >= need_fast) {
        float* reps   = (float*)d_ws;
        float* psum   = reps + (size_t)kB * kG;
        float* psumsq = psum + (size_t)kYB * kG;
        float* acoef  = psumsq + (size_t)kYB * kG;
        float* cval   = acoef + kG;
        pass1<true><<<dim3(kG / 4, kYB), 256, 0, stream>>>(
            x, idxw, W, reps, psum, psumsq);
        pass2<<<1, kG, 0, stream>>>(psum, psumsq, gamma, beta, fcw, fcb,
                                    acoef, cval);
        pass3<<<kB / 4, 256, 0, stream>>>(reps, acoef, cval, out);
    } else {
        float* psum   = (float*)d_ws;
        float* psumsq = psum + (size_t)kYB * kG;
        float* acoef  = psumsq + (size_t)kYB * kG;
        float* cval   = acoef + kG;
        float* logit  = cval + 4;
        hipMemsetAsync(logit, 0, kB * sizeof(float), stream);
        pass1<false><<<dim3(kG / 4, kYB), 256, 0, stream>>>(
            x, idxw, W, nullptr, psum, psumsq);
        pass2<<<1, kG, 0, stream>>>(psum, psumsq, gamma, beta, fcw, fcb,
                                    acoef, cval);
        pass3_re<<<dim3(kG / 4, kYB), 256, 0, stream>>>(
            x, idxw, W, acoef, logit);
        pass4<<<kB / 256, 256, 0, stream>>>(logit, cval, out);
    }
}